// Round 4
// baseline (132.273 us; speedup 1.0000x reference)
//
#include <hip/hip_runtime.h>
#include <hip/hip_bf16.h>
#include <math.h>

// NT-Xent loss, N=4096, D=256, symmetric-GEMM version.
// loss = (1/2N) * sum_i [ 2 + log( sum_{j != i} exp(2*dot_ij - 2) ) - 2*dot(zn_i, zn_pair(i)) ]
// K1: normalize rows -> bf16 zn in ws; zero rowtotal[8192], ticket and out.
// K2: PERSISTENT 128x256 tiles: 264 blocks x 4 consecutive tiles each (1056
//     tiles over the upper triangle), 512 thr = 8 waves 2x4. Single-buffered
//     LDS per tile (stage -> sync -> compute -> sync). Fused epilogue per tile:
//     exp row/col sums -> rowtotal via global atomics, pair tiles add the
//     -2*pair_dot terms to out. NO per-block fence (rounds 1-2: per-block
//     __threadfence = L2 writeback storm, +120 us). Last block via fence-free
//     ticket computes loss += sum_i (2 + log(rowtotal[i])) / 2N.

using short8  = __attribute__((ext_vector_type(8))) short;
using floatx4 = __attribute__((ext_vector_type(4))) float;

constexpr int TWO_N = 8192;
constexpr int DIM   = 256;
constexpr int NJB   = 32;                // 256-wide column blocks
constexpr int NTILE = NJB * (NJB + 1);   // 1056 tiles: per jbb, ib in [0, 2*jbb+2)
constexpr int TPB   = 4;                 // tiles per persistent block
constexpr int NBLK  = NTILE / TPB;       // 264 blocks
constexpr float INV2N = 1.0f / 8192.0f;

__device__ static inline unsigned short f2bf(float f) {
  unsigned u = __float_as_uint(f);
  return (unsigned short)((u + 0x7fffu + ((u >> 16) & 1u)) >> 16);  // RNE
}

__device__ static inline void async_copy16(const __hip_bfloat16* g, __hip_bfloat16* l) {
  __builtin_amdgcn_global_load_lds(
      (const __attribute__((address_space(1))) void*)(const void*)g,
      (__attribute__((address_space(3))) void*)(void*)l, 16, 0, 0);
}

// ---------------- K1: normalize + cast to bf16, zero accumulators ----------------
__global__ __launch_bounds__(256) void k_normalize(
    const float* __restrict__ zi, const float* __restrict__ zj,
    __hip_bfloat16* __restrict__ zn, float* __restrict__ rowtotal,
    float* __restrict__ out, unsigned* __restrict__ ticket)
{
  if (blockIdx.x == 0 && threadIdx.x == 0) { out[0] = 0.0f; ticket[0] = 0u; }
  if (blockIdx.x < 32) rowtotal[blockIdx.x * 256 + threadIdx.x] = 0.0f;

  const int lane = threadIdx.x & 63;
  const int wave = threadIdx.x >> 6;
  const int row  = blockIdx.x * 4 + wave;
  const float* src = (row < 4096) ? (zi + (size_t)row * DIM)
                                  : (zj + (size_t)(row - 4096) * DIM);
  float4 v = reinterpret_cast<const float4*>(src)[lane];
  float ss = v.x * v.x + v.y * v.y + v.z * v.z + v.w * v.w;
#pragma unroll
  for (int m = 32; m >= 1; m >>= 1) ss += __shfl_xor(ss, m, 64);
  float inv = 1.0f / fmaxf(sqrtf(ss), 1e-8f);
  ushort4 o;
  o.x = f2bf(v.x * inv); o.y = f2bf(v.y * inv);
  o.z = f2bf(v.z * inv); o.w = f2bf(v.w * inv);
  reinterpret_cast<ushort4*>(zn + (size_t)row * DIM)[lane] = o;
}

// ---------------- K2: persistent 128x256 triangular GEMM + fused epilogue ----------------
// LDS S[384][64] bf16: rows 0-127 = A tile (128 rows of ib), rows 128-383 = B tile
// (256 rows of jbb). 16B-slot XOR swizzle: phys_slot = logical ^ (row&7).
// Wave (wm = wave>>2, wn = wave&3) owns out rows wm*64..+63, cols wn*64..+63.
// Column half h = wn>>1 maps to 128-col block jb_h = 2*jbb + h.
__global__ __launch_bounds__(512) void k_simexp(
    const __hip_bfloat16* __restrict__ Z, float* __restrict__ rowtotal,
    float* __restrict__ out, unsigned* __restrict__ ticket)
{
  __shared__ __align__(16) __hip_bfloat16 S[384 * 64];
  __shared__ float rowsum[128];
  __shared__ float colsum[256];
  __shared__ float finsum[8];
  __shared__ int lastflag;

  const int tid  = threadIdx.x;
  const int lane = tid & 63;
  const int wave = tid >> 6;     // 0..7
  const int wm   = wave >> 2;    // 0..1: row half (64 rows)
  const int wn   = wave & 3;     // 0..3: col quarter (64 cols)

  const int lane7 = lane & 7;
  const int sub   = lane >> 3;               // subrow within an 8-row copy
  const int gkoff = ((lane7 ^ sub) << 3);    // swizzled logical 16B slot to fetch
  const int q     = lane >> 4;               // 0..3
  const int c16   = lane & 15;

  for (int t = 0; t < TPB; ++t) {
    const int u = blockIdx.x * TPB + t;      // consecutive tiles share jbb panel

    // decode: u -> (jbb, ib), ib in [0, 2*jbb+2); cumulative C(j)=j*(j+1)
    int jbb = (int)((sqrtf(4.0f * (float)u + 1.0f) - 1.0f) * 0.5f);
    while ((jbb + 1) * (jbb + 2) <= u) ++jbb;
    while (jbb * (jbb + 1) > u) --jbb;
    const int ib = u - jbb * (jbb + 1);

    const int i0  = ib * 128;
    const int j00 = jbb * 256;

    // per-wave half flags
    const int  h        = wn >> 1;
    const int  jb_h     = 2 * jbb + h;
    const bool valid    = (jb_h >= ib);      // false only for h=0 when ib==2*jbb+1
    const bool diagblk  = (jb_h == ib);
    const bool pairblk  = (jb_h == ib + 32);
    const int  wn_in    = wn & 1;
    const bool diagwave = (wm == wn_in);     // wave sits on the half-tile diagonal

    if (t) __syncthreads();                  // prev tile's flush reads of row/colsum done
    if (tid < 128) rowsum[tid] = 0.0f;
    if (tid < 256) colsum[tid] = 0.0f;

    floatx4 acc[4][4] = {};

    for (int kk = 0; kk < 4; ++kk) {
      const int k0 = kk * 64;
      // stage 384 rows x 64 cols: 8 waves x 6 copies x 8 rows
#pragma unroll
      for (int c = 0; c < 6; ++c) {
        const int rrb  = wave * 48 + c * 8;            // wave-uniform LDS row base
        const int rr   = rrb + sub;                    // this lane's source row
        const int grow = (rr < 128) ? (i0 + rr) : (j00 + rr - 128);
        async_copy16(Z + (size_t)grow * DIM + k0 + gkoff, S + rrb * 64);
      }
      __syncthreads();

      const __hip_bfloat16* Bb = S + 128 * 64;
#pragma unroll
      for (int ks = 0; ks < 2; ++ks) {
        const int phys = (ks * 4 + q) ^ lane7;  // physical 16B slot for this lane
        short8 a[4], b[4];
#pragma unroll
        for (int mt = 0; mt < 4; ++mt)
          a[mt] = *reinterpret_cast<const short8*>(
              S + (wm * 64 + mt * 16 + c16) * 64 + phys * 8);
#pragma unroll
        for (int nt = 0; nt < 4; ++nt)
          b[nt] = *reinterpret_cast<const short8*>(
              Bb + (wn * 64 + nt * 16 + c16) * 64 + phys * 8);
#pragma unroll
        for (int mt = 0; mt < 4; ++mt)
#pragma unroll
          for (int nt = 0; nt < 4; ++nt)
            acc[mt][nt] = __builtin_amdgcn_mfma_f32_16x16x32_bf16(
                a[mt], b[nt], acc[mt][nt], 0, 0, 0);
      }
      __syncthreads();
    }

    // ---- epilogue ----
    // C/D layout: col = lane&15 (within nt-tile), row = q*4 + reg (within mt-tile).
    float colacc[4] = {0.f, 0.f, 0.f, 0.f};
    float pc = 0.f;

#pragma unroll
    for (int mt = 0; mt < 4; ++mt) {
#pragma unroll
      for (int reg = 0; reg < 4; ++reg) {
        const bool onquad = (c16 == q * 4 + reg);  // lane holds a subtile-diag elem
        float s = 0.0f;
#pragma unroll
        for (int nt = 0; nt < 4; ++nt) {
          float e = __expf(2.0f * acc[mt][nt][reg] - 2.0f);
          bool skip = diagblk && diagwave && (nt == mt) && onquad;  // true self-sim
          s += skip ? 0.0f : e;
          colacc[nt] += e;
        }
        if (pairblk && diagwave && onquad) pc += acc[mt][mt][reg];  // pair dot
        s += __shfl_xor(s, 1, 64);
        s += __shfl_xor(s, 2, 64);
        s += __shfl_xor(s, 4, 64);
        s += __shfl_xor(s, 8, 64);
        if (valid && c16 == 0)
          atomicAdd(&rowsum[wm * 64 + mt * 16 + q * 4 + reg], s);
      }
    }

    if (valid && !diagblk) {
#pragma unroll
      for (int nt = 0; nt < 4; ++nt) {
        float cs = colacc[nt];
        cs += __shfl_xor(cs, 16, 64);
        cs += __shfl_xor(cs, 32, 64);
        if (lane < 16) atomicAdd(&colsum[wn * 64 + nt * 16 + lane], cs);
      }
    }

    if (pairblk && diagwave) {
#pragma unroll
      for (int m = 32; m >= 1; m >>= 1) pc += __shfl_xor(pc, m, 64);
      // each pair diag elem covers rows i and i+4096: loss += -2*(2*dot) per pair
      if (lane == 0) atomicAdd(out, -4.0f * pc * INV2N);
    }

    __syncthreads();
    if (tid < 128) {
      atomicAdd(&rowtotal[i0 + tid], rowsum[tid]);
    } else if (tid < 384) {
      const int tcol = tid - 128;          // 0..255: column within the 256-col tile
      const int jb_t = 2 * jbb + (tcol >> 7);
      if (jb_t > ib)                       // valid and not the diagonal half
        atomicAdd(&rowtotal[jb_t * 128 + (tcol & 127)], colsum[tcol]);
    }
  }

  // ---- fence-free ticket finalize: last block reduces rowtotal -> out ----
  // __syncthreads drains vmcnt(0): all this block's device-scope rowtotal
  // atomics have executed at the coherence point before the ticket bump.
  __syncthreads();
  if (tid == 0) lastflag = (atomicAdd(ticket, 1u) == (unsigned)(NBLK - 1)) ? 1 : 0;
  __syncthreads();
  if (lastflag) {
    __threadfence();      // acquire side; runs in ONE block only (cheap)
    float v = 0.0f;
#pragma unroll 4
    for (int r = tid; r < TWO_N; r += 512) {
      float tv = __hip_atomic_load(&rowtotal[r], __ATOMIC_RELAXED,
                                   __HIP_MEMORY_SCOPE_AGENT);
      v += 2.0f + __logf(tv);
    }
#pragma unroll
    for (int m = 32; m >= 1; m >>= 1) v += __shfl_xor(v, m, 64);
    if (lane == 0) finsum[wave] = v;
    __syncthreads();
    if (tid == 0) {
      float acc8 = 0.0f;
#pragma unroll
      for (int w = 0; w < 8; ++w) acc8 += finsum[w];
      atomicAdd(out, acc8 * INV2N);
    }
  }
}

// ---------------- launch ----------------
extern "C" void kernel_launch(void* const* d_in, const int* in_sizes, int n_in,
                              void* d_out, int out_size, void* d_ws, size_t ws_size,
                              hipStream_t stream) {
  const float* zi = (const float*)d_in[0];
  const float* zj = (const float*)d_in[1];
  float* out = (float*)d_out;

  __hip_bfloat16* zn = (__hip_bfloat16*)d_ws;                        // 8192*256*2 = 4 MB
  float* rowtotal = (float*)((char*)d_ws + (size_t)TWO_N * DIM * 2); // 8192*4 = 32 KB
  unsigned* ticket = (unsigned*)((char*)d_ws + (size_t)TWO_N * DIM * 2 + (size_t)TWO_N * 4);

  k_normalize<<<dim3(TWO_N / 4), dim3(256), 0, stream>>>(zi, zj, zn, rowtotal, out, ticket);
  k_simexp<<<dim3(NBLK), dim3(512), 0, stream>>>(zn, rowtotal, out, ticket);
}

// Round 7
// 103.001 us; speedup vs baseline: 1.2842x; 1.2842x over previous
//
#include <hip/hip_runtime.h>
#include <hip/hip_bf16.h>
#include <math.h>

// NT-Xent loss, N=4096, D=256, symmetric-GEMM version.
// loss = (1/2N) * sum_i [ 2 + log( sum_{j != i} exp(2*dot_ij - 2) ) - 2*dot(zn_i, zn_pair(i)) ]
// K1: normalize rows -> bf16 zn in ws; zero rowtotal[8192] and out.
// K2: upper-triangular 128x128 bf16 MFMA tiles (2080 blocks, 256 thr = 4 waves).
//     REG-STAGED prefetch (T14 issue-early/write-late) under FULL __syncthreads
//     fences: global->reg loads for step kk+1 issue BEFORE compute(kk); the
//     barrier's mandatory vmcnt(0) drain lands after the compute phase, hiding
//     the L2 latency. ds_write regs -> LDS after the barrier, cheap lgkm
//     barrier, next step. No raw s_barrier / counted vmcnt (rounds 5-6: that
//     protocol intermittently races -- m152 lesson). Round-0 memory model.
//     Fused epilogue: exp row/col sums -> rowtotal (global atomics), diag tiles
//     skip self-sim, pair tiles add -2*pair_dot into out.
// K3: 32 blocks: loss += sum_i (2 + log(rowtotal[i])) / 2N.

using short8  = __attribute__((ext_vector_type(8))) short;
using floatx4 = __attribute__((ext_vector_type(4))) float;

constexpr int TWO_N = 8192;
constexpr int DIM   = 256;
constexpr int NB    = 64;                 // 8192/128 tile blocks per side
constexpr int NTRI  = NB * (NB + 1) / 2;  // 2080
constexpr float INV2N = 1.0f / 8192.0f;

__device__ static inline unsigned short f2bf(float f) {
  unsigned u = __float_as_uint(f);
  return (unsigned short)((u + 0x7fffu + ((u >> 16) & 1u)) >> 16);  // RNE
}

// ---------------- K1: normalize + cast to bf16, zero accumulators ----------------
__global__ __launch_bounds__(256) void k_normalize(
    const float* __restrict__ zi, const float* __restrict__ zj,
    __hip_bfloat16* __restrict__ zn, float* __restrict__ rowtotal,
    float* __restrict__ out)
{
  if (blockIdx.x == 0 && threadIdx.x == 0) out[0] = 0.0f;
  if (blockIdx.x < 32) rowtotal[blockIdx.x * 256 + threadIdx.x] = 0.0f;

  const int lane = threadIdx.x & 63;
  const int wave = threadIdx.x >> 6;
  const int row  = blockIdx.x * 4 + wave;
  const float* src = (row < 4096) ? (zi + (size_t)row * DIM)
                                  : (zj + (size_t)(row - 4096) * DIM);
  float4 v = reinterpret_cast<const float4*>(src)[lane];
  float ss = v.x * v.x + v.y * v.y + v.z * v.z + v.w * v.w;
#pragma unroll
  for (int m = 32; m >= 1; m >>= 1) ss += __shfl_xor(ss, m, 64);
  float inv = 1.0f / fmaxf(sqrtf(ss), 1e-8f);
  ushort4 o;
  o.x = f2bf(v.x * inv); o.y = f2bf(v.y * inv);
  o.z = f2bf(v.z * inv); o.w = f2bf(v.w * inv);
  reinterpret_cast<ushort4*>(zn + (size_t)row * DIM)[lane] = o;
}

// ---------------- K2: triangular GEMM, reg-staged prefetch pipeline ----------------
// block 256 = 4 waves in 2x2; wave owns 64x64 (4x4 of 16x16x32 accumulators).
// LDS tiles [128][64] bf16 with 16B-slot XOR swizzle: phys_slot = logical ^ (row&7).
// Staging (identical addresses to the round-0 DMA version): lane writes its 16B
// (global row c*8+sub, k-slot lane7^sub) to LDS elems c*512 + lane*8.
__global__ __launch_bounds__(256) void k_simexp(
    const __hip_bfloat16* __restrict__ Z, float* __restrict__ rowtotal,
    float* __restrict__ out)
{
  __shared__ __align__(16) __hip_bfloat16 As[128 * 64];
  __shared__ __align__(16) __hip_bfloat16 Bs[128 * 64];
  __shared__ float rowsum[128];
  __shared__ float colsum[128];

  const int tid  = threadIdx.x;
  const int lane = tid & 63;
  const int wave = tid >> 6;
  const int wm   = wave >> 1;   // output row half
  const int wn   = wave & 1;    // output col half

  // triangular decode: blockIdx.x -> (ib <= jb)
  const int u = blockIdx.x;
  int jb = (int)((sqrtf(8.0f * (float)u + 1.0f) - 1.0f) * 0.5f);
  while ((jb + 1) * (jb + 2) / 2 <= u) ++jb;
  while (jb * (jb + 1) / 2 > u) --jb;
  const int ib = u - jb * (jb + 1) / 2;

  const bool diagblk = (ib == jb);
  const bool pairblk = (jb == ib + 32);
  const int i0 = ib * 128;
  const int j0 = jb * 128;

  if (tid < 128) { rowsum[tid] = 0.0f; colsum[tid] = 0.0f; }

  floatx4 acc[4][4] = {};

  const int lane7 = lane & 7;
  const int sub   = lane >> 3;               // 0..7 subrow within 8-row segment
  const int gkoff = ((lane7 ^ sub) << 3);    // swizzled logical 16B slot to fetch
  const int q     = lane >> 4;               // 0..3
  const int c16   = lane & 15;

  // staging bases: waves 0,1 -> As (rows 0..63 / 64..127), waves 2,3 -> Bs
  const __hip_bfloat16* gbase =
      Z + (size_t)((wave < 2 ? i0 : j0) + (wave & 1) * 64) * DIM;
  __hip_bfloat16* lbase = ((wave < 2) ? As : Bs) + (wave & 1) * 64 * 64;

  short8 r[8];

  // prologue: stage kk=0 through regs
#pragma unroll
  for (int c = 0; c < 8; ++c)
    r[c] = *reinterpret_cast<const short8*>(
        gbase + (size_t)(c * 8 + sub) * DIM + gkoff);
#pragma unroll
  for (int c = 0; c < 8; ++c)
    *reinterpret_cast<short8*>(lbase + c * 512 + lane * 8) = r[c];
  __syncthreads();

#pragma unroll
  for (int kk = 0; kk < 4; ++kk) {
    // issue next step's global loads FIRST; they land during compute(kk)
    if (kk < 3) {
      const int k0 = (kk + 1) * 64;
#pragma unroll
      for (int c = 0; c < 8; ++c)
        r[c] = *reinterpret_cast<const short8*>(
            gbase + (size_t)(c * 8 + sub) * DIM + k0 + gkoff);
      __builtin_amdgcn_sched_barrier(0);  // pin loads here (don't sink past compute)
    }

    // compute step kk from LDS
#pragma unroll
    for (int ks = 0; ks < 2; ++ks) {
      const int phys = (ks * 4 + q) ^ lane7;  // physical 16B slot for this lane
      short8 a[4], b[4];
#pragma unroll
      for (int mt = 0; mt < 4; ++mt)
        a[mt] = *reinterpret_cast<const short8*>(
            As + (wm * 64 + mt * 16 + c16) * 64 + phys * 8);
#pragma unroll
      for (int nt = 0; nt < 4; ++nt)
        b[nt] = *reinterpret_cast<const short8*>(
            Bs + (wn * 64 + nt * 16 + c16) * 64 + phys * 8);
#pragma unroll
      for (int mt = 0; mt < 4; ++mt)
#pragma unroll
        for (int nt = 0; nt < 4; ++nt)
          acc[mt][nt] = __builtin_amdgcn_mfma_f32_16x16x32_bf16(
              a[mt], b[nt], acc[mt][nt], 0, 0, 0);
    }

    __syncthreads();   // all waves done reading; vmcnt(0) drain lands AFTER compute
    if (kk < 3) {
#pragma unroll
      for (int c = 0; c < 8; ++c)
        *reinterpret_cast<short8*>(lbase + c * 512 + lane * 8) = r[c];
      __syncthreads(); // lgkm-only drain: writes visible for compute(kk+1)
    }
  }

  // ---- epilogue ----
  // C/D layout: col = lane&15 (within nt-tile), row = q*4 + reg (within mt-tile).
  float colacc[4] = {0.f, 0.f, 0.f, 0.f};
  float pc = 0.f;
  const bool diagwave = (wm == wn);

#pragma unroll
  for (int mt = 0; mt < 4; ++mt) {
#pragma unroll
    for (int reg = 0; reg < 4; ++reg) {
      const bool onquad = (c16 == q * 4 + reg);  // lane holds a subtile-diag elem
      float s = 0.0f;
#pragma unroll
      for (int nt = 0; nt < 4; ++nt) {
        float e = __expf(2.0f * acc[mt][nt][reg] - 2.0f);
        bool skip = diagblk && diagwave && (nt == mt) && onquad;  // true self-sim
        s += skip ? 0.0f : e;
        colacc[nt] += e;
      }
      if (pairblk && diagwave && onquad) pc += acc[mt][mt][reg];  // pair dot
      s += __shfl_xor(s, 1, 64);
      s += __shfl_xor(s, 2, 64);
      s += __shfl_xor(s, 4, 64);
      s += __shfl_xor(s, 8, 64);
      if (c16 == 0)
        atomicAdd(&rowsum[wm * 64 + mt * 16 + q * 4 + reg], s);
    }
  }

  if (!diagblk) {
#pragma unroll
    for (int nt = 0; nt < 4; ++nt) {
      float cs = colacc[nt];
      cs += __shfl_xor(cs, 16, 64);
      cs += __shfl_xor(cs, 32, 64);
      if (lane < 16) atomicAdd(&colsum[wn * 64 + nt * 16 + lane], cs);
    }
  }

  if (pairblk && diagwave) {
#pragma unroll
    for (int m = 32; m >= 1; m >>= 1) pc += __shfl_xor(pc, m, 64);
    // each pair diag elem covers rows i and i+4096: loss += -2*(2*dot) per pair
    if (lane == 0) atomicAdd(out, -4.0f * pc * INV2N);
  }

  __syncthreads();
  if (tid < 128) {
    atomicAdd(&rowtotal[i0 + tid], rowsum[tid]);
    if (!diagblk) atomicAdd(&rowtotal[j0 + tid], colsum[tid]);
  }
}

// ---------------- K3: finalize (logs + reduce) ----------------
__global__ __launch_bounds__(256) void k_finalize(
    const float* __restrict__ rowtotal, float* __restrict__ out)
{
  __shared__ float wsum[4];
  const int lane = threadIdx.x & 63;
  const int wave = threadIdx.x >> 6;
  const int row  = blockIdx.x * 256 + threadIdx.x;
  float v = 2.0f + __logf(rowtotal[row]);
#pragma unroll
  for (int m = 32; m >= 1; m >>= 1) v += __shfl_xor(v, m, 64);
  if (lane == 0) wsum[wave] = v;
  __syncthreads();
  if (threadIdx.x == 0)
    atomicAdd(out, (wsum[0] + wsum[1] + wsum[2] + wsum[3]) * INV2N);
}

// ---------------- launch ----------------
extern "C" void kernel_launch(void* const* d_in, const int* in_sizes, int n_in,
                              void* d_out, int out_size, void* d_ws, size_t ws_size,
                              hipStream_t stream) {
  const float* zi = (const float*)d_in[0];
  const float* zj = (const float*)d_in[1];
  float* out = (float*)d_out;

  __hip_bfloat16* zn = (__hip_bfloat16*)d_ws;                        // 8192*256*2 = 4 MB
  float* rowtotal = (float*)((char*)d_ws + (size_t)TWO_N * DIM * 2); // 8192*4 = 32 KB

  k_normalize<<<dim3(TWO_N / 4), dim3(256), 0, stream>>>(zi, zj, zn, rowtotal, out);
  k_simexp<<<dim3(NTRI), dim3(256), 0, stream>>>(zn, rowtotal, out);
  k_finalize<<<dim3(TWO_N / 256), dim3(256), 0, stream>>>(rowtotal, out);
}